// Round 2
// baseline (375.961 us; speedup 1.0000x reference)
//
#include <hip/hip_runtime.h>
#include <math.h>

// Problem constants
// z: (B=16, C=512, H=64, W=64) f32 ; codebook: (K=2048, D=64)
// tokens N = B*H*W = 65536, token t = b*4096 + hw
#define TOK_PER_BLK 128

// ---------------- prep kernels ----------------

__global__ void k_prep_wi(const float* __restrict__ v, const float* __restrict__ g,
                          float* __restrict__ wi){
  const int d = blockIdx.x;          // 64 blocks
  const int tid = threadIdx.x;       // 256
  float s = 0.f;
  for (int c = tid; c < 512; c += 256){ float x = v[d*512+c]; s = fmaf(x,x,s); }
  __shared__ float red[4];
  #pragma unroll
  for (int o = 32; o > 0; o >>= 1) s += __shfl_down(s, o);
  if ((tid & 63) == 0) red[tid >> 6] = s;
  __syncthreads();
  const float nrm = sqrtf(red[0]+red[1]+red[2]+red[3]);
  const float gd = g[d];
  for (int c = tid; c < 512; c += 256) wi[d*512+c] = gd * v[d*512+c] / nrm;
}

__global__ void k_prep_wo(const float* __restrict__ v, const float* __restrict__ g,
                          float* __restrict__ wot){
  const int c = blockIdx.x;          // 512 blocks
  const int d = threadIdx.x;         // 64 (one wave)
  const float x = v[c*64+d];
  float s = x*x;
  #pragma unroll
  for (int o = 32; o > 0; o >>= 1) s += __shfl_down(s, o);
  const float nrm = __shfl(sqrtf(s), 0);
  wot[d*512 + c] = g[c] * x / nrm;   // transposed store WoT[d][c]
}

// Table[k][c] = sum_d cb[k][d] * WoT[d][c] + ob[c];  ne[k] = sum_d cb[k][d]^2
__global__ void k_table(const float* __restrict__ cbk, const float* __restrict__ wot,
                        const float* __restrict__ ob, float* __restrict__ table,
                        float* __restrict__ ne){
  const int k = blockIdx.x;          // 2048 blocks
  const int tid = threadIdx.x;       // 512
  __shared__ float e[64];
  if (tid < 64) e[tid] = cbk[k*64 + tid];
  __syncthreads();
  if (tid < 64){
    float x = e[tid];
    float s = x*x;
    #pragma unroll
    for (int o = 32; o > 0; o >>= 1) s += __shfl_down(s, o);
    if (tid == 0) ne[k] = s;
  }
  const int c = tid;
  float acc = ob[c];
  #pragma unroll 16
  for (int d = 0; d < 64; d++) acc = fmaf(e[d], wot[d*512 + c], acc);
  table[(size_t)k*512 + c] = acc;
}

// ---------------- main fused kernel ----------------
// Per block: 128 tokens (one b, contiguous hw).
// Phase 1: z_e[d][t] into LDS (reg-tiled 4t x 8d per thread).
// Phase 2: argmin over 2048 codes, chunks of 128 (reg-tiled 8t x 8k).
// Then: cross-thread argmin reduce, loss recompute, Table-gather output.
__global__ __launch_bounds__(256, 2) void k_main(
    const float* __restrict__ z, const float* __restrict__ cbk,
    const float* __restrict__ wi, const float* __restrict__ inb,
    const float* __restrict__ ne, const float* __restrict__ table,
    float* __restrict__ out, float* __restrict__ oidx, double* __restrict__ loss)
{
  __shared__ __align__(16) float ze_s[64*132];   // [d][t] padded
  __shared__ __align__(16) float sbuf[64*132];   // phase1: z_s+wi_s ; phase2: cb_s ; then reduce
  __shared__ int bidx_s[128];

  const int tid = threadIdx.x;
  const int t0  = blockIdx.x * TOK_PER_BLK;
  const int b   = t0 >> 12;
  const int hw0 = t0 & 4095;
  const float* zb = z + ((size_t)b << 21) + hw0;     // b*512*4096

  // ---- phase 1: z_e = Wi @ z + in_b ----
  float* z_s  = sbuf;               // [32][132]
  float* wi_s = sbuf + 32*132;      // [32][68]
  float acc1[4][8];
  #pragma unroll
  for (int j = 0; j < 4; j++)
    #pragma unroll
    for (int i = 0; i < 8; i++) acc1[j][i] = 0.f;

  const int tt = tid & 31;          // token group: tokens tt*4 .. tt*4+3
  const int dg = tid >> 5;          // d group: d = dg*8 .. dg*8+7

  for (int c0 = 0; c0 < 512; c0 += 32){
    { // stage z chunk [32 c][128 t]
      const int cc = tid >> 3, colb = (tid & 7) * 16;
      const float* src = zb + (size_t)(c0 + cc) * 4096 + colb;
      float* dst = &z_s[cc*132 + colb];
      #pragma unroll
      for (int j = 0; j < 4; j++)
        *(float4*)(dst + 4*j) = *(const float4*)(src + 4*j);
    }
    { // stage Wi^T chunk [32 c][64 d]
      #pragma unroll
      for (int j = 0; j < 8; j++){
        const int flat = tid + 256*j;
        const int d = flat >> 5, cc = flat & 31;
        wi_s[cc*68 + d] = wi[d*512 + c0 + cc];
      }
    }
    __syncthreads();
    #pragma unroll 4
    for (int cc = 0; cc < 32; cc++){
      const float4 zv = *(const float4*)&z_s[cc*132 + tt*4];
      const float4 wa = *(const float4*)&wi_s[cc*68 + dg*8];
      const float4 wb = *(const float4*)&wi_s[cc*68 + dg*8 + 4];
      const float zzv[4] = {zv.x, zv.y, zv.z, zv.w};
      const float wwv[8] = {wa.x, wa.y, wa.z, wa.w, wb.x, wb.y, wb.z, wb.w};
      #pragma unroll
      for (int j = 0; j < 4; j++)
        #pragma unroll
        for (int i = 0; i < 8; i++)
          acc1[j][i] = fmaf(zzv[j], wwv[i], acc1[j][i]);
    }
    __syncthreads();
  }
  #pragma unroll
  for (int i = 0; i < 8; i++){
    const int d = dg*8 + i;
    const float bd = inb[d];
    #pragma unroll
    for (int j = 0; j < 4; j++)
      ze_s[d*132 + tt*4 + j] = acc1[j][i] + bd;
  }
  __syncthreads();

  // ---- phase 2: distances + argmin ----
  float* cb_s = sbuf;               // [64][132] (staged as -2*cb, transposed)
  const int tg = tid & 15;          // tokens tg*8 .. tg*8+7
  const int kg = tid >> 4;          // codes kg*8 .. kg*8+7 within 128-chunk
  float best[8]; int bidx[8];
  #pragma unroll
  for (int j = 0; j < 8; j++){ best[j] = INFINITY; bidx[j] = 0; }

  for (int kc = 0; kc < 2048; kc += 128){
    #pragma unroll
    for (int j = 0; j < 32; j++){
      const int flat = tid + 256*j;
      const int kk = flat >> 6, d = flat & 63;
      cb_s[d*132 + kk] = -2.0f * cbk[(size_t)(kc + kk)*64 + d];
    }
    __syncthreads();
    float acc[8][8];                // [t][k], init with ||e||^2
    #pragma unroll
    for (int i = 0; i < 8; i++){
      const float nv = ne[kc + kg*8 + i];
      #pragma unroll
      for (int j = 0; j < 8; j++) acc[j][i] = nv;
    }
    #pragma unroll 4
    for (int d = 0; d < 64; d++){
      const float4 za  = *(const float4*)&ze_s[d*132 + tg*8];
      const float4 zb4 = *(const float4*)&ze_s[d*132 + tg*8 + 4];
      const float4 ca  = *(const float4*)&cb_s[d*132 + kg*8];
      const float4 cb4 = *(const float4*)&cb_s[d*132 + kg*8 + 4];
      const float zzv[8] = {za.x, za.y, za.z, za.w, zb4.x, zb4.y, zb4.z, zb4.w};
      const float ccv[8] = {ca.x, ca.y, ca.z, ca.w, cb4.x, cb4.y, cb4.z, cb4.w};
      #pragma unroll
      for (int j = 0; j < 8; j++)
        #pragma unroll
        for (int i = 0; i < 8; i++)
          acc[j][i] = fmaf(zzv[j], ccv[i], acc[j][i]);
    }
    #pragma unroll
    for (int i = 0; i < 8; i++){
      const int k = kc + kg*8 + i;
      #pragma unroll
      for (int j = 0; j < 8; j++)
        if (acc[j][i] < best[j]){ best[j] = acc[j][i]; bidx[j] = k; }
    }
    __syncthreads();
  }

  // ---- cross-thread argmin reduce (16 threads per token) ----
  float* rb = sbuf;                  // [128][16]
  int*   ri = (int*)(sbuf + 2048);   // [128][16]
  #pragma unroll
  for (int j = 0; j < 8; j++){
    const int t = tg*8 + j;
    rb[t*16 + kg] = best[j];
    ri[t*16 + kg] = bidx[j];
  }
  __syncthreads();

  float myloss = 0.f;
  if (tid < 128){
    const int t = tid;
    float bv = rb[t*16]; int bi = ri[t*16];
    #pragma unroll
    for (int q = 1; q < 16; q++){
      const float vq = rb[t*16 + q]; const int iq = ri[t*16 + q];
      if (vq < bv || (vq == bv && iq < bi)){ bv = vq; bi = iq; }
    }
    bidx_s[t] = bi;
    oidx[t0 + t] = (float)bi;        // indices output (as float in flat f32 buffer)
    // loss: sum_d (z_e - e)^2, elementwise (matches reference formula)
    const float* e = cbk + (size_t)bi * 64;
    #pragma unroll 8
    for (int d = 0; d < 64; d++){
      const float diff = ze_s[d*132 + t] - e[d];
      myloss = fmaf(diff, diff, myloss);
    }
  }
  #pragma unroll
  for (int o = 32; o > 0; o >>= 1) myloss += __shfl_down(myloss, o);
  if (tid < 128 && (tid & 63) == 0) atomicAdd(loss, (double)myloss);
  __syncthreads();

  // ---- output: out[b][c][hw] = Table[idx][c] ----
  {
    const int tl = tid & 127, cg = tid >> 7;
    const int myk = bidx_s[tl];
    const float* trow = table + ((size_t)myk << 9) + cg*256;
    float* ob = out + (((size_t)b) << 21) + hw0 + tl;
    #pragma unroll 4
    for (int ci = 0; ci < 64; ci++){
      const float4 v = *(const float4*)(trow + ci*4);
      const size_t cbase = (size_t)(cg*256 + ci*4) << 12;
      ob[cbase        ] = v.x;
      ob[cbase +  4096] = v.y;
      ob[cbase +  8192] = v.z;
      ob[cbase + 12288] = v.w;
    }
  }
}

__global__ void k_finish(const double* __restrict__ loss, float* __restrict__ oloss){
  *oloss = (float)(1.25 * (*loss) / 4194304.0);   // 1.25 * mean over B*D*H*W
}

// ---------------- launch ----------------

extern "C" void kernel_launch(void* const* d_in, const int* in_sizes, int n_in,
                              void* d_out, int out_size, void* d_ws, size_t ws_size,
                              hipStream_t stream) {
  const float* z   = (const float*)d_in[0];
  const float* cbk = (const float*)d_in[1];
  const float* inv = (const float*)d_in[2];
  const float* ing = (const float*)d_in[3];
  const float* inb = (const float*)d_in[4];
  const float* ov  = (const float*)d_in[5];
  const float* og  = (const float*)d_in[6];
  const float* ob  = (const float*)d_in[7];

  float* ws    = (float*)d_ws;
  float* wi    = ws;                       // [64][512]
  float* wot   = ws + 32768;               // [64][512] (WoT[d][c])
  float* table = ws + 65536;               // [2048][512]
  float* ne    = ws + 65536 + 1048576;     // [2048]
  double* loss = (double*)(ws + 65536 + 1048576 + 2048);  // 8B, aligned

  float* out   = (float*)d_out;            // [16][512][4096]
  float* oidx  = out + 33554432;           // [65536] indices as float
  float* oloss = out + 33619968;           // scalar

  hipMemsetAsync(loss, 0, sizeof(double), stream);
  k_prep_wi<<<64, 256, 0, stream>>>(inv, ing, wi);
  k_prep_wo<<<512, 64, 0, stream>>>(ov, og, wot);
  k_table<<<2048, 512, 0, stream>>>(cbk, wot, ob, table, ne);
  k_main<<<512, 256, 0, stream>>>(z, cbk, wi, inb, ne, table, out, oidx, loss);
  k_finish<<<1, 1, 0, stream>>>(loss, oloss);
}

// Round 3
// 340.108 us; speedup vs baseline: 1.1054x; 1.1054x over previous
//
#include <hip/hip_runtime.h>
#include <math.h>

// z: (B=16, C=512, H=64, W=64) f32 ; codebook: (K=2048, D=64)
// tokens N = B*H*W = 65536, token t = b*4096 + hw

// ---------------- prep kernels ----------------

// wiT[c][d] = g[d] * v[d][c] / ||v[d,:]||
__global__ void k_prep_wi(const float* __restrict__ v, const float* __restrict__ g,
                          float* __restrict__ wiT){
  const int d = blockIdx.x;          // 64
  const int tid = threadIdx.x;       // 256
  float s = 0.f;
  for (int c = tid; c < 512; c += 256){ float x = v[d*512+c]; s = fmaf(x,x,s); }
  __shared__ float red[4];
  #pragma unroll
  for (int o = 32; o > 0; o >>= 1) s += __shfl_down(s, o);
  if ((tid & 63) == 0) red[tid >> 6] = s;
  __syncthreads();
  const float nrm = sqrtf(red[0]+red[1]+red[2]+red[3]);
  const float gd = g[d];
  for (int c = tid; c < 512; c += 256) wiT[c*64 + d] = gd * v[d*512+c] / nrm;
}

__global__ void k_prep_wo(const float* __restrict__ v, const float* __restrict__ g,
                          float* __restrict__ wot){
  const int c = blockIdx.x;          // 512
  const int d = threadIdx.x;         // 64
  const float x = v[c*64+d];
  float s = x*x;
  #pragma unroll
  for (int o = 32; o > 0; o >>= 1) s += __shfl_down(s, o);
  const float nrm = __shfl(sqrtf(s), 0);
  wot[d*512 + c] = g[c] * x / nrm;   // WoT[d][c]
}

// Table[k][c] = sum_d cb[k][d]*WoT[d][c] + ob[c];  ne[k] = ||cb[k]||^2
__global__ void k_table(const float* __restrict__ cbk, const float* __restrict__ wot,
                        const float* __restrict__ ob, float* __restrict__ table,
                        float* __restrict__ ne){
  const int k = blockIdx.x;          // 2048
  const int tid = threadIdx.x;       // 512
  __shared__ float e[64];
  if (tid < 64) e[tid] = cbk[k*64 + tid];
  __syncthreads();
  if (tid < 64){
    float x = e[tid];
    float s = x*x;
    #pragma unroll
    for (int o = 32; o > 0; o >>= 1) s += __shfl_down(s, o);
    if (tid == 0) ne[k] = s;
  }
  const int c = tid;
  float acc = ob[c];
  #pragma unroll 16
  for (int d = 0; d < 64; d++) acc = fmaf(e[d], wot[d*512 + c], acc);
  table[(size_t)k*512 + c] = acc;
}

// ---------------- phase 1: in_proj -> z_e to global [d][t] ----------------
// 256 tokens/block, grid 256. tile 8t x 8d per thread, reg-prefetch staging.
__global__ __launch_bounds__(256, 1) void k_inproj(
    const float* __restrict__ z, const float* __restrict__ wiT,
    const float* __restrict__ inb, float* __restrict__ ze)
{
  __shared__ __align__(16) float z_s[16*256];   // 16 KB [c][t]
  __shared__ __align__(16) float wi_s[16*68];   // 4.4 KB [c][d]
  const int tid = threadIdx.x;
  const int T0  = blockIdx.x << 8;
  const int b   = T0 >> 12;
  const int hw0 = T0 & 4095;
  const float* zb = z + ((size_t)b << 21) + hw0;

  const int tgp = tid & 31;          // tokens tgp*4..+3 and 128+tgp*4..+3
  const int dgp = tid >> 5;          // d = dgp*8..+7
  const int ccb = tid >> 6;          // staging row base
  const int c64 = tid & 63;          // staging col

  float acc[8][8];                   // [d][t]
  #pragma unroll
  for (int i = 0; i < 8; i++)
    #pragma unroll
    for (int j = 0; j < 8; j++) acc[i][j] = 0.f;

  float4 pz[4]; float pw[4];
  // prologue: load c0=0
  #pragma unroll
  for (int q = 0; q < 4; q++){
    pz[q] = *(const float4*)(zb + (size_t)(ccb + 4*q) * 4096 + c64*4);
    pw[q] = wiT[(ccb + 4*q)*64 + c64];
  }
  #pragma unroll
  for (int q = 0; q < 4; q++){
    *(float4*)&z_s[(ccb + 4*q)*256 + c64*4] = pz[q];
    wi_s[(ccb + 4*q)*68 + c64] = pw[q];
  }
  __syncthreads();

  for (int c0 = 0;;){
    const int nxt = c0 + 16;
    if (nxt < 512){
      #pragma unroll
      for (int q = 0; q < 4; q++){
        pz[q] = *(const float4*)(zb + (size_t)(nxt + ccb + 4*q) * 4096 + c64*4);
        pw[q] = wiT[(nxt + ccb + 4*q)*64 + c64];
      }
    }
    #pragma unroll 4
    for (int cc = 0; cc < 16; cc++){
      const float4 ta = *(const float4*)&z_s[cc*256 + tgp*4];
      const float4 tb = *(const float4*)&z_s[cc*256 + 128 + tgp*4];
      const float4 w0 = *(const float4*)&wi_s[cc*68 + dgp*8];
      const float4 w1 = *(const float4*)&wi_s[cc*68 + dgp*8 + 4];
      const float tv[8] = {ta.x,ta.y,ta.z,ta.w, tb.x,tb.y,tb.z,tb.w};
      const float wv[8] = {w0.x,w0.y,w0.z,w0.w, w1.x,w1.y,w1.z,w1.w};
      #pragma unroll
      for (int i = 0; i < 8; i++)
        #pragma unroll
        for (int j = 0; j < 8; j++)
          acc[i][j] = fmaf(tv[j], wv[i], acc[i][j]);
    }
    if (nxt >= 512) break;
    __syncthreads();
    #pragma unroll
    for (int q = 0; q < 4; q++){
      *(float4*)&z_s[(ccb + 4*q)*256 + c64*4] = pz[q];
      wi_s[(ccb + 4*q)*68 + c64] = pw[q];
    }
    __syncthreads();
    c0 = nxt;
  }

  // epilogue: + in_b, coalesced float4 stores to ze[d][T0+t]
  #pragma unroll
  for (int i = 0; i < 8; i++){
    const int d = dgp*8 + i;
    const float bd = inb[d];
    float4 o0 = {acc[i][0]+bd, acc[i][1]+bd, acc[i][2]+bd, acc[i][3]+bd};
    float4 o1 = {acc[i][4]+bd, acc[i][5]+bd, acc[i][6]+bd, acc[i][7]+bd};
    *(float4*)(ze + (size_t)d*65536 + T0 + tgp*4)       = o0;
    *(float4*)(ze + (size_t)d*65536 + T0 + 128 + tgp*4) = o1;
  }
}

// ---------------- phase 2: distances + argmin + loss + gather ----------------
// 128 tokens/block, grid 512. tile 8t x 16k, codebook staged in d-halves.
__global__ __launch_bounds__(256, 2) void k_main2(
    const float* __restrict__ ze, const float* __restrict__ cbk,
    const float* __restrict__ ne, const float* __restrict__ table,
    float* __restrict__ out, float* __restrict__ oidx, double* __restrict__ loss)
{
  __shared__ __align__(16) float ze_s[64*128];   // 32 KB [d][t]
  __shared__ __align__(16) float cb_s[32*260];   // 33.3 KB [d][k] (-2*cb), padded
  __shared__ int bidx_s[128];

  const int tid = threadIdx.x;
  const int t0  = blockIdx.x << 7;
  const int b   = t0 >> 12;
  const int hw0 = t0 & 4095;

  // stage z_e tile [64][128]
  #pragma unroll
  for (int j = 0; j < 8; j++){
    const int idx = tid + 256*j;
    const int row = idx >> 5, col4 = idx & 31;
    *(float4*)&ze_s[row*128 + col4*4] =
        *(const float4*)(ze + (size_t)row*65536 + t0 + col4*4);
  }

  const int tg = tid & 15;           // tokens tg*4..+3 and 64+tg*4..+3
  const int kg = tid >> 4;           // codes kg*16..+15 within 256-chunk
  float best[8]; int bidx[8];
  #pragma unroll
  for (int j = 0; j < 8; j++){ best[j] = INFINITY; bidx[j] = 0; }

  float acc[8][16];
  float4 pv[8];
  // prologue: load stage 0 codebook (chunk 0, d 0..31)
  {
    const float* src = cbk + (size_t)tid * 64;
    #pragma unroll
    for (int q = 0; q < 8; q++) pv[q] = *(const float4*)(src + q*4);
  }

  for (int s = 0; s < 16; s++){       // stage: chunk = s>>1 (256 codes), dh = s&1
    __syncthreads();
    // write cb_s from regs (bank-sequential scalar stores)
    #pragma unroll
    for (int q = 0; q < 8; q++){
      const float* p = (const float*)&pv[q];
      #pragma unroll
      for (int r = 0; r < 4; r++) cb_s[(q*4+r)*260 + tid] = -2.0f * p[r];
    }
    if (s < 15){
      const int s1 = s + 1;
      const float* src = cbk + (size_t)(((s1 >> 1) << 8) + tid) * 64 + (s1 & 1)*32;
      #pragma unroll
      for (int q = 0; q < 8; q++) pv[q] = *(const float4*)(src + q*4);
    }
    __syncthreads();

    const int dh = s & 1, kc = (s >> 1) << 8;
    if (dh == 0){
      #pragma unroll
      for (int q = 0; q < 4; q++){
        const float4 nv = *(const float4*)&ne[kc + kg*16 + q*4];
        const float nn[4] = {nv.x, nv.y, nv.z, nv.w};
        #pragma unroll
        for (int r = 0; r < 4; r++)
          #pragma unroll
          for (int j = 0; j < 8; j++) acc[j][q*4+r] = nn[r];
      }
    }
    const int dbase = dh << 5;
    #pragma unroll 4
    for (int d = 0; d < 32; d++){
      const int dr = dbase + d;
      const float4 za = *(const float4*)&ze_s[dr*128 + tg*4];
      const float4 zb = *(const float4*)&ze_s[dr*128 + 64 + tg*4];
      const float4 c0 = *(const float4*)&cb_s[d*260 + kg*16];
      const float4 c1 = *(const float4*)&cb_s[d*260 + kg*16 + 4];
      const float4 c2 = *(const float4*)&cb_s[d*260 + kg*16 + 8];
      const float4 c3 = *(const float4*)&cb_s[d*260 + kg*16 + 12];
      const float zz[8]  = {za.x,za.y,za.z,za.w, zb.x,zb.y,zb.z,zb.w};
      const float cv[16] = {c0.x,c0.y,c0.z,c0.w, c1.x,c1.y,c1.z,c1.w,
                            c2.x,c2.y,c2.z,c2.w, c3.x,c3.y,c3.z,c3.w};
      #pragma unroll
      for (int j = 0; j < 8; j++)
        #pragma unroll
        for (int i = 0; i < 16; i++)
          acc[j][i] = fmaf(zz[j], cv[i], acc[j][i]);
    }
    if (dh == 1){
      #pragma unroll
      for (int i = 0; i < 16; i++){
        const int k = kc + kg*16 + i;
        #pragma unroll
        for (int j = 0; j < 8; j++)
          if (acc[j][i] < best[j]){ best[j] = acc[j][i]; bidx[j] = k; }
      }
    }
  }
  __syncthreads();

  // cross-thread argmin reduce (16 threads per token), overlay on cb_s
  float* rb = cb_s;
  int*   ri = (int*)(cb_s + 2048);
  #pragma unroll
  for (int j = 0; j < 8; j++){
    const int t = (j < 4) ? (tg*4 + j) : (64 + tg*4 + (j - 4));
    rb[t*16 + kg] = best[j];
    ri[t*16 + kg] = bidx[j];
  }
  __syncthreads();

  float myloss = 0.f;
  if (tid < 128){
    const int t = tid;
    float bv = rb[t*16]; int bi = ri[t*16];
    #pragma unroll
    for (int q = 1; q < 16; q++){
      const float vq = rb[t*16 + q]; const int iq = ri[t*16 + q];
      if (vq < bv || (vq == bv && iq < bi)){ bv = vq; bi = iq; }
    }
    bidx_s[t] = bi;
    oidx[t0 + t] = (float)bi;
    const float* e = cbk + (size_t)bi * 64;
    #pragma unroll 8
    for (int d = 0; d < 64; d++){
      const float diff = ze_s[d*128 + t] - e[d];
      myloss = fmaf(diff, diff, myloss);
    }
  }
  #pragma unroll
  for (int o = 32; o > 0; o >>= 1) myloss += __shfl_down(myloss, o);
  if (tid < 128 && (tid & 63) == 0) atomicAdd(loss, (double)myloss);
  __syncthreads();

  // output gather: out[b][c][hw] = Table[idx][c]
  {
    const int tl = tid & 127, cg = tid >> 7;
    const int myk = bidx_s[tl];
    const float* trow = table + ((size_t)myk << 9) + cg*256;
    float* ob = out + (((size_t)b) << 21) + hw0 + tl;
    #pragma unroll 4
    for (int ci = 0; ci < 64; ci++){
      const float4 v = *(const float4*)(trow + ci*4);
      const size_t cbase = (size_t)(cg*256 + ci*4) << 12;
      ob[cbase        ] = v.x;
      ob[cbase +  4096] = v.y;
      ob[cbase +  8192] = v.z;
      ob[cbase + 12288] = v.w;
    }
  }
}

__global__ void k_finish(const double* __restrict__ loss, float* __restrict__ oloss){
  *oloss = (float)(1.25 * (*loss) / 4194304.0);   // 1.25 * mean over B*D*H*W
}

// ---------------- launch ----------------

extern "C" void kernel_launch(void* const* d_in, const int* in_sizes, int n_in,
                              void* d_out, int out_size, void* d_ws, size_t ws_size,
                              hipStream_t stream) {
  const float* z   = (const float*)d_in[0];
  const float* cbk = (const float*)d_in[1];
  const float* inv = (const float*)d_in[2];
  const float* ing = (const float*)d_in[3];
  const float* inb = (const float*)d_in[4];
  const float* ov  = (const float*)d_in[5];
  const float* og  = (const float*)d_in[6];
  const float* ob  = (const float*)d_in[7];

  float* ws    = (float*)d_ws;
  float* wiT   = ws;                       // [512][64]
  float* wot   = ws + 32768;               // [64][512]
  float* table = ws + 65536;               // [2048][512]
  float* ne    = ws + 65536 + 1048576;     // [2048]
  double* loss = (double*)(ws + 1116160);  // 8B aligned
  float* zebuf = ws + 2097152;             // [64][65536] = 16 MB

  float* out   = (float*)d_out;            // [16][512][4096]
  float* oidx  = out + 33554432;           // [65536]
  float* oloss = out + 33619968;           // scalar

  hipMemsetAsync(loss, 0, sizeof(double), stream);
  k_prep_wi<<<64, 256, 0, stream>>>(inv, ing, wiT);
  k_prep_wo<<<512, 64, 0, stream>>>(ov, og, wot);
  k_table<<<2048, 512, 0, stream>>>(cbk, wot, ob, table, ne);
  k_inproj<<<256, 256, 0, stream>>>(z, wiT, inb, zebuf);
  k_main2<<<512, 256, 0, stream>>>(zebuf, cbk, ne, table, out, oidx, loss);
  k_finish<<<1, 1, 0, stream>>>(loss, oloss);
}